// Round 1
// baseline (562.396 us; speedup 1.0000x reference)
//
#include <hip/hip_runtime.h>
#include <hip/hip_bf16.h>
#include <stdint.h>

// BinaryDense: out[8192,4096] = x[8192,4096] @ sign(kernel[4096,4096]) + bias[4096]
// Strategy: sign(w) is exact in bf16 (+-1, 0); x->bf16 rounding error ~0.07 std
// per output, way under the 2%-of-absmax threshold. So: convert, transpose W,
// then m97-style bf16 MFMA GEMM (128x128 tile, BK=32, global_load_lds w=16).

typedef __bf16 bf16x8 __attribute__((ext_vector_type(8)));
typedef float floatx4 __attribute__((ext_vector_type(4)));
typedef unsigned short ushortx8 __attribute__((ext_vector_type(8)));

constexpr int M = 8192, N = 4096, K = 4096;
constexpr int BM = 128, BN = 128, BK = 32;

__device__ __forceinline__ void gload_lds16(const void* g, void* l) {
  __builtin_amdgcn_global_load_lds(
      (const __attribute__((address_space(1))) unsigned int*)g,
      (__attribute__((address_space(3))) unsigned int*)l, 16, 0, 0);
}

// fp32 -> bf16 bits, round-to-nearest-even (manual, header-version-proof)
__device__ __forceinline__ unsigned short f2bf(float f) {
  unsigned int b = __builtin_bit_cast(unsigned int, f);
  b += 0x7FFFu + ((b >> 16) & 1u);
  return (unsigned short)(b >> 16);
}

// ---- kernel 1: x fp32 -> bf16 (8 elems/thread, 32B in / 16B out) ----
__global__ __launch_bounds__(256) void cvt_x_kernel(const float* __restrict__ x,
                                                    unsigned short* __restrict__ xb) {
  size_t i = ((size_t)blockIdx.x * 256 + threadIdx.x) * 8;
  float4 f0 = *(const float4*)(x + i);
  float4 f1 = *(const float4*)(x + i + 4);
  ushortx8 o;
  o[0] = f2bf(f0.x); o[1] = f2bf(f0.y); o[2] = f2bf(f0.z); o[3] = f2bf(f0.w);
  o[4] = f2bf(f1.x); o[5] = f2bf(f1.y); o[6] = f2bf(f1.z); o[7] = f2bf(f1.w);
  *(ushortx8*)(xb + i) = o;
}

// ---- kernel 2: Wt[n][k] = sign(w[k][n]) as bf16 bits (LDS tile transpose) ----
__global__ __launch_bounds__(256) void sign_t_kernel(const float* __restrict__ w,
                                                     unsigned short* __restrict__ wt) {
  __shared__ unsigned short tile[32][33];
  const int n0 = blockIdx.x * 32, k0 = blockIdx.y * 32;
  const int tx = threadIdx.x, ty = threadIdx.y;  // (32, 8)
#pragma unroll
  for (int i = 0; i < 4; ++i) {
    int kk = ty + i * 8;
    float v = w[(size_t)(k0 + kk) * N + n0 + tx];
    tile[kk][tx] = (v > 0.f) ? 0x3F80u : (v < 0.f ? 0xBF80u : 0u);
  }
  __syncthreads();
#pragma unroll
  for (int i = 0; i < 4; ++i) {
    int nn = ty + i * 8;
    wt[(size_t)(n0 + nn) * K + k0 + tx] = tile[tx][nn];
  }
}

// ---- kernel 3: bf16 MFMA GEMM, m97 structure ----
// A = Xb [M][K] bf16, B = Wt [N][K] bf16 (pre-transposed), C = out [M][N] fp32
__global__ __launch_bounds__(256) void gemm_bin_kernel(
    const unsigned short* __restrict__ Xb,
    const unsigned short* __restrict__ Wt,
    const float* __restrict__ bias,
    float* __restrict__ out) {
  __shared__ unsigned short Alds[BM * BK];  // 8 KB
  __shared__ unsigned short Blds[BN * BK];  // 8 KB

  const int tid = threadIdx.x;
  const int w = tid >> 6;
  const int lane = tid & 63;
  const int wm = w & 1, wn = w >> 1;   // 2x2 wave grid -> 64x64 per wave
  const int m0 = blockIdx.y * BM;
  const int n0 = blockIdx.x * BN;
  const int quad = lane >> 4;   // k-chunk: k = quad*8 + j
  const int l16 = lane & 15;    // m (A) / n (B) index within 16

  floatx4 acc[4][4];
#pragma unroll
  for (int i = 0; i < 4; ++i)
#pragma unroll
    for (int j = 0; j < 4; ++j)
      acc[i][j] = (floatx4){0.f, 0.f, 0.f, 0.f};

  for (int k0 = 0; k0 < K; k0 += BK) {
    // stage A,B tiles: chunk c = 8 bf16 = 16B; 512 chunks each; 2 iters x 256 thr
    // lds dest is wave-uniform base + lane*16 (global_load_lds semantics)
#pragma unroll
    for (int it = 0; it < 2; ++it) {
      int c = it * 256 + tid;
      gload_lds16(Xb + (size_t)(m0 + (c >> 2)) * K + k0 + (c & 3) * 8,
                  Alds + (size_t)(it * 256 + w * 64) * 8);
    }
#pragma unroll
    for (int it = 0; it < 2; ++it) {
      int c = it * 256 + tid;
      gload_lds16(Wt + (size_t)(n0 + (c >> 2)) * K + k0 + (c & 3) * 8,
                  Blds + (size_t)(it * 256 + w * 64) * 8);
    }
    __syncthreads();  // emits s_waitcnt vmcnt(0) before s_barrier

    bf16x8 a[4], b[4];
#pragma unroll
    for (int mi = 0; mi < 4; ++mi) {
      int r = wm * 64 + mi * 16 + l16;
      a[mi] = *(const bf16x8*)(Alds + r * BK + quad * 8);
    }
#pragma unroll
    for (int ni = 0; ni < 4; ++ni) {
      int r = wn * 64 + ni * 16 + l16;
      b[ni] = *(const bf16x8*)(Blds + r * BK + quad * 8);
    }
#pragma unroll
    for (int mi = 0; mi < 4; ++mi)
#pragma unroll
      for (int ni = 0; ni < 4; ++ni)
        acc[mi][ni] = __builtin_amdgcn_mfma_f32_16x16x32_bf16(a[mi], b[ni], acc[mi][ni], 0, 0, 0);

    __syncthreads();
  }

  // epilogue: C/D layout col=lane&15, row=quad*4+reg (verified m89/m91)
#pragma unroll
  for (int ni = 0; ni < 4; ++ni) {
    int col = n0 + wn * 64 + ni * 16 + l16;
    float bv = bias[col];
#pragma unroll
    for (int mi = 0; mi < 4; ++mi) {
      int rbase = m0 + wm * 64 + mi * 16 + quad * 4;
#pragma unroll
      for (int r = 0; r < 4; ++r)
        out[(size_t)(rbase + r) * N + col] = acc[mi][ni][r] + bv;
    }
  }
}

extern "C" void kernel_launch(void* const* d_in, const int* in_sizes, int n_in,
                              void* d_out, int out_size, void* d_ws, size_t ws_size,
                              hipStream_t stream) {
  const float* x = (const float*)d_in[0];
  const float* kern = (const float*)d_in[1];
  const float* bias = (const float*)d_in[2];
  float* out = (float*)d_out;

  unsigned short* Xb = (unsigned short*)d_ws;                          // 64 MiB
  unsigned short* Wt = (unsigned short*)((char*)d_ws + (size_t)M * K * 2);  // 32 MiB

  cvt_x_kernel<<<(M * K / 8) / 256, 256, 0, stream>>>(x, Xb);
  sign_t_kernel<<<dim3(N / 32, K / 32), dim3(32, 8), 0, stream>>>(kern, Wt);
  gemm_bin_kernel<<<dim3(N / BN, M / BM), 256, 0, stream>>>(Xb, Wt, bias, out);
}

// Round 2
// 555.586 us; speedup vs baseline: 1.0123x; 1.0123x over previous
//
#include <hip/hip_runtime.h>
#include <hip/hip_bf16.h>
#include <stdint.h>

// BinaryDense: out[8192,4096] = x[8192,4096] @ sign(kernel[4096,4096]) + bias[4096]
// bf16 MFMA route (sign(w) exact in bf16; x->bf16 error absmax 2.0 vs thr 7.32).
// R2: XOR chunk-swizzle in GEMM LDS layout to kill ds_read_b128 8-way bank
// conflicts (3.35e7 -> target <1e7); sign_t rewritten 64x64 tile w/ 16B stores.

typedef __bf16 bf16x8 __attribute__((ext_vector_type(8)));
typedef float floatx4 __attribute__((ext_vector_type(4)));
typedef unsigned short ushortx8 __attribute__((ext_vector_type(8)));
typedef unsigned short ushortx4 __attribute__((ext_vector_type(4)));

constexpr int M = 8192, N = 4096, K = 4096;
constexpr int BM = 128, BN = 128, BK = 32;

__device__ __forceinline__ void gload_lds16(const void* g, void* l) {
  __builtin_amdgcn_global_load_lds(
      (const __attribute__((address_space(1))) unsigned int*)g,
      (__attribute__((address_space(3))) unsigned int*)l, 16, 0, 0);
}

// fp32 -> bf16 bits, round-to-nearest-even
__device__ __forceinline__ unsigned short f2bf(float f) {
  unsigned int b = __builtin_bit_cast(unsigned int, f);
  b += 0x7FFFu + ((b >> 16) & 1u);
  return (unsigned short)(b >> 16);
}

// ---- kernel 1: x fp32 -> bf16 (8 elems/thread, 32B in / 16B out) ----
__global__ __launch_bounds__(256) void cvt_x_kernel(const float* __restrict__ x,
                                                    unsigned short* __restrict__ xb) {
  size_t i = ((size_t)blockIdx.x * 256 + threadIdx.x) * 8;
  float4 f0 = *(const float4*)(x + i);
  float4 f1 = *(const float4*)(x + i + 4);
  ushortx8 o;
  o[0] = f2bf(f0.x); o[1] = f2bf(f0.y); o[2] = f2bf(f0.z); o[3] = f2bf(f0.w);
  o[4] = f2bf(f1.x); o[5] = f2bf(f1.y); o[6] = f2bf(f1.z); o[7] = f2bf(f1.w);
  *(ushortx8*)(xb + i) = o;
}

// ---- kernel 2: Wt[n][k] = sign(w[k][n]) as bf16 bits; 64x64 LDS transpose ----
// load: float4/lane (256B segments); store: ushort8/lane (128B segments)
__global__ __launch_bounds__(256) void sign_t_kernel(const float* __restrict__ w,
                                                     unsigned short* __restrict__ wt) {
  constexpr int PAD = 72;  // ushorts; 144B row stride, 8B-aligned stores
  __shared__ unsigned short tile[64 * PAD];
  const int n0 = blockIdx.x * 64, k0 = blockIdx.y * 64;
  const int t = threadIdx.x;
#pragma unroll
  for (int i = 0; i < 4; ++i) {
    int kl = (t >> 4) + i * 16;      // 0..63
    int nl = (t & 15) * 4;           // 0..60
    float4 v = *(const float4*)(w + (size_t)(k0 + kl) * N + n0 + nl);
    ushortx4 s;
    s[0] = (v.x > 0.f) ? 0x3F80u : (v.x < 0.f ? 0xBF80u : 0u);
    s[1] = (v.y > 0.f) ? 0x3F80u : (v.y < 0.f ? 0xBF80u : 0u);
    s[2] = (v.z > 0.f) ? 0x3F80u : (v.z < 0.f ? 0xBF80u : 0u);
    s[3] = (v.w > 0.f) ? 0x3F80u : (v.w < 0.f ? 0xBF80u : 0u);
    *(ushortx4*)(tile + kl * PAD + nl) = s;
  }
  __syncthreads();
#pragma unroll
  for (int i = 0; i < 2; ++i) {
    int nl = (t >> 3) + i * 32;      // 0..63
    int kk = (t & 7) * 8;            // 0..56
    ushortx8 o;
#pragma unroll
    for (int j = 0; j < 8; ++j) o[j] = tile[(kk + j) * PAD + nl];
    *(ushortx8*)(wt + (size_t)(n0 + nl) * K + k0 + kk) = o;
  }
}

// ---- kernel 3: bf16 MFMA GEMM, m97 structure + XOR chunk swizzle ----
// A = Xb [M][K] bf16, B = Wt [N][K] bf16, C = out [M][N] fp32
// LDS layout: row r's 16B chunk q lives at slot q ^ ((r>>1)&3); we steer the
// per-lane GLOBAL address so the wave-uniform-dest DMA lands chunks swizzled.
__global__ __launch_bounds__(256) void gemm_bin_kernel(
    const unsigned short* __restrict__ Xb,
    const unsigned short* __restrict__ Wt,
    const float* __restrict__ bias,
    float* __restrict__ out) {
  __shared__ unsigned short Alds[BM * BK];  // 8 KB
  __shared__ unsigned short Blds[BN * BK];  // 8 KB

  const int tid = threadIdx.x;
  const int w = tid >> 6;
  const int lane = tid & 63;
  const int wm = w & 1, wn = w >> 1;   // 2x2 wave grid -> 64x64 per wave
  const int m0 = blockIdx.y * BM;
  const int n0 = blockIdx.x * BN;
  const int quad = lane >> 4;   // k-chunk: k = quad*8 + j
  const int l16 = lane & 15;    // m (A) / n (B) index within 16

  floatx4 acc[4][4];
#pragma unroll
  for (int i = 0; i < 4; ++i)
#pragma unroll
    for (int j = 0; j < 4; ++j)
      acc[i][j] = (floatx4){0.f, 0.f, 0.f, 0.f};

  for (int k0 = 0; k0 < K; k0 += BK) {
#pragma unroll
    for (int it = 0; it < 2; ++it) {
      int p = it * 256 + tid;                 // LDS chunk position
      int row = p >> 2;
      int chunk = (p & 3) ^ ((row >> 1) & 3); // which global chunk lives here
      gload_lds16(Xb + (size_t)(m0 + row) * K + k0 + chunk * 8,
                  Alds + (size_t)(it * 256 + w * 64) * 8);
    }
#pragma unroll
    for (int it = 0; it < 2; ++it) {
      int p = it * 256 + tid;
      int row = p >> 2;
      int chunk = (p & 3) ^ ((row >> 1) & 3);
      gload_lds16(Wt + (size_t)(n0 + row) * K + k0 + chunk * 8,
                  Blds + (size_t)(it * 256 + w * 64) * 8);
    }
    __syncthreads();

    bf16x8 a[4], b[4];
#pragma unroll
    for (int mi = 0; mi < 4; ++mi) {
      int r = wm * 64 + mi * 16 + l16;
      int cpos = (r << 2) | (quad ^ ((r >> 1) & 3));
      a[mi] = *(const bf16x8*)(Alds + cpos * 8);
    }
#pragma unroll
    for (int ni = 0; ni < 4; ++ni) {
      int r = wn * 64 + ni * 16 + l16;
      int cpos = (r << 2) | (quad ^ ((r >> 1) & 3));
      b[ni] = *(const bf16x8*)(Blds + cpos * 8);
    }
#pragma unroll
    for (int mi = 0; mi < 4; ++mi)
#pragma unroll
      for (int ni = 0; ni < 4; ++ni)
        acc[mi][ni] = __builtin_amdgcn_mfma_f32_16x16x32_bf16(a[mi], b[ni], acc[mi][ni], 0, 0, 0);

    __syncthreads();
  }

  // epilogue: C/D layout col=lane&15, row=quad*4+reg (verified m89/m91)
#pragma unroll
  for (int ni = 0; ni < 4; ++ni) {
    int col = n0 + wn * 64 + ni * 16 + l16;
    float bv = bias[col];
#pragma unroll
    for (int mi = 0; mi < 4; ++mi) {
      int rbase = m0 + wm * 64 + mi * 16 + quad * 4;
#pragma unroll
      for (int r = 0; r < 4; ++r)
        out[(size_t)(rbase + r) * N + col] = acc[mi][ni][r] + bv;
    }
  }
}

extern "C" void kernel_launch(void* const* d_in, const int* in_sizes, int n_in,
                              void* d_out, int out_size, void* d_ws, size_t ws_size,
                              hipStream_t stream) {
  const float* x = (const float*)d_in[0];
  const float* kern = (const float*)d_in[1];
  const float* bias = (const float*)d_in[2];
  float* out = (float*)d_out;

  unsigned short* Xb = (unsigned short*)d_ws;                               // 64 MiB
  unsigned short* Wt = (unsigned short*)((char*)d_ws + (size_t)M * K * 2);  // 32 MiB

  cvt_x_kernel<<<(M * K / 8) / 256, 256, 0, stream>>>(x, Xb);
  sign_t_kernel<<<dim3(N / 64, K / 64), dim3(256), 0, stream>>>(kern, Wt);
  gemm_bin_kernel<<<dim3(N / BN, M / BM), 256, 0, stream>>>(Xb, Wt, bias, out);
}

// Round 3
// 429.524 us; speedup vs baseline: 1.3093x; 1.2935x over previous
//
#include <hip/hip_runtime.h>
#include <stdint.h>

// BinaryDense: out[8192,4096] = x[8192,4096] @ sign(kernel[4096,4096]) + bias[4096]
// R3: int8 route. sign(w) exact in i8; x quantized per-row (scale=127/rowmax,
// exact int32 accumulation). mfma_i32_16x16x64_i8: K=64/instr at 2x bf16 rate,
// same 16B/lane fragments -> same LDS/DMA structure as R2, half the K-iters.
// Error model: sigma=0.58, max~3.4 (+2.0 bf16-compare ulp) vs threshold 7.32.

typedef int int4v __attribute__((ext_vector_type(4)));

constexpr int M = 8192, N = 4096, K = 4096;
constexpr int BM = 128, BN = 128, BK = 64;  // BK in i8 elements (= bytes)

__device__ __forceinline__ void gload_lds16(const void* g, void* l) {
  __builtin_amdgcn_global_load_lds(
      (const __attribute__((address_space(1))) unsigned int*)g,
      (__attribute__((address_space(3))) unsigned int*)l, 16, 0, 0);
}

// ---- kernel 1: per-row absmax quantize x -> i8; rscale[row] = rowmax/127 ----
__global__ __launch_bounds__(256) void quant_x_kernel(const float* __restrict__ x,
                                                      signed char* __restrict__ xq,
                                                      float* __restrict__ rscale) {
  const int row = blockIdx.x;
  const int t = threadIdx.x;
  const float* xr = x + (size_t)row * K;
  float4 v[4];
  float mx = 0.f;
#pragma unroll
  for (int i = 0; i < 4; ++i) {
    v[i] = *(const float4*)(xr + t * 16 + i * 4);
    mx = fmaxf(mx, fmaxf(fmaxf(fabsf(v[i].x), fabsf(v[i].y)),
                         fmaxf(fabsf(v[i].z), fabsf(v[i].w))));
  }
#pragma unroll
  for (int off = 32; off >= 1; off >>= 1)
    mx = fmaxf(mx, __shfl_xor(mx, off, 64));
  __shared__ float smax[4];
  if ((t & 63) == 0) smax[t >> 6] = mx;
  __syncthreads();
  const float rm = fmaxf(fmaxf(smax[0], smax[1]), fmaxf(smax[2], smax[3]));
  const float s = (rm > 0.f) ? 127.f / rm : 0.f;
  if (t == 0) rscale[row] = (rm > 0.f) ? rm / 127.f : 0.f;
  uint32_t o[4];
#pragma unroll
  for (int i = 0; i < 4; ++i) {
    float f[4] = {v[i].x, v[i].y, v[i].z, v[i].w};
    uint32_t p = 0;
#pragma unroll
    for (int j = 0; j < 4; ++j) {
      int q = (int)rintf(f[j] * s);  // in [-127,127] by construction
      p |= ((uint32_t)(uint8_t)(signed char)q) << (8 * j);
    }
    o[i] = p;
  }
  *(int4v*)(xq + (size_t)row * K + t * 16) = (int4v){(int)o[0], (int)o[1], (int)o[2], (int)o[3]};
}

// ---- kernel 2: Wq[n][k] = sign(w[k][n]) as i8; 64x64 LDS transpose ----
__global__ __launch_bounds__(256) void sign_t_kernel(const float* __restrict__ w,
                                                     signed char* __restrict__ wq) {
  __shared__ __align__(16) signed char tile[64 * 68];  // pad 68 (4-aligned rows)
  const int n0 = blockIdx.x * 64, k0 = blockIdx.y * 64;
  const int t = threadIdx.x;
#pragma unroll
  for (int i = 0; i < 4; ++i) {
    int kl = (t >> 4) + i * 16;  // 0..63
    int nl = (t & 15) * 4;       // 0..60
    float4 v = *(const float4*)(w + (size_t)(k0 + kl) * N + n0 + nl);
    uint32_t p = 0;
    p |= ((uint32_t)(uint8_t)(signed char)((v.x > 0.f) - (v.x < 0.f)));
    p |= ((uint32_t)(uint8_t)(signed char)((v.y > 0.f) - (v.y < 0.f))) << 8;
    p |= ((uint32_t)(uint8_t)(signed char)((v.z > 0.f) - (v.z < 0.f))) << 16;
    p |= ((uint32_t)(uint8_t)(signed char)((v.w > 0.f) - (v.w < 0.f))) << 24;
    *(uint32_t*)(tile + kl * 68 + nl) = p;
  }
  __syncthreads();
  const int nl = t >> 2;          // 0..63
  const int kc = (t & 3) * 16;    // 0,16,32,48
  uint32_t o[4] = {0, 0, 0, 0};
#pragma unroll
  for (int j = 0; j < 16; ++j)
    o[j >> 2] |= ((uint32_t)(uint8_t)tile[(kc + j) * 68 + nl]) << (8 * (j & 3));
  *(int4v*)(wq + (size_t)(n0 + nl) * K + k0 + kc) =
      (int4v){(int)o[0], (int)o[1], (int)o[2], (int)o[3]};
}

// ---- kernel 3: i8 MFMA GEMM, m97 structure + XOR chunk swizzle ----
// A = Xq [M][K] i8, B = Wq [N][K] i8, acc int32 (exact), dequant in epilogue.
// LDS layout: row r's 16B chunk q lives at slot q ^ ((r>>1)&3).
__global__ __launch_bounds__(256) void gemm_bin_kernel(
    const signed char* __restrict__ Xq,
    const signed char* __restrict__ Wq,
    const float* __restrict__ rscale,
    const float* __restrict__ bias,
    float* __restrict__ out) {
  __shared__ __align__(16) signed char Alds[BM * BK];  // 8 KB
  __shared__ __align__(16) signed char Blds[BN * BK];  // 8 KB

  const int tid = threadIdx.x;
  const int w = tid >> 6;
  const int lane = tid & 63;
  const int wm = w & 1, wn = w >> 1;  // 2x2 wave grid -> 64x64 per wave
  const int m0 = blockIdx.y * BM;
  const int n0 = blockIdx.x * BN;
  const int quad = lane >> 4;  // k-chunk: k = quad*16 + byte
  const int l16 = lane & 15;   // m (A) / n (B) index within 16

  int4v acc[4][4];
#pragma unroll
  for (int i = 0; i < 4; ++i)
#pragma unroll
    for (int j = 0; j < 4; ++j)
      acc[i][j] = (int4v){0, 0, 0, 0};

  for (int k0 = 0; k0 < K; k0 += BK) {  // 64 iters
#pragma unroll
    for (int it = 0; it < 2; ++it) {
      int p = it * 256 + tid;                  // LDS chunk position
      int row = p >> 2;
      int chunk = (p & 3) ^ ((row >> 1) & 3);  // which global chunk lands here
      gload_lds16(Xq + (size_t)(m0 + row) * K + k0 + chunk * 16,
                  Alds + (size_t)(it * 256 + w * 64) * 16);
    }
#pragma unroll
    for (int it = 0; it < 2; ++it) {
      int p = it * 256 + tid;
      int row = p >> 2;
      int chunk = (p & 3) ^ ((row >> 1) & 3);
      gload_lds16(Wq + (size_t)(n0 + row) * K + k0 + chunk * 16,
                  Blds + (size_t)(it * 256 + w * 64) * 16);
    }
    __syncthreads();

    int4v a[4], b[4];
#pragma unroll
    for (int mi = 0; mi < 4; ++mi) {
      int r = wm * 64 + mi * 16 + l16;
      int cpos = (r << 2) | (quad ^ ((r >> 1) & 3));
      a[mi] = *(const int4v*)(Alds + (size_t)cpos * 16);
    }
#pragma unroll
    for (int ni = 0; ni < 4; ++ni) {
      int r = wn * 64 + ni * 16 + l16;
      int cpos = (r << 2) | (quad ^ ((r >> 1) & 3));
      b[ni] = *(const int4v*)(Blds + (size_t)cpos * 16);
    }
#pragma unroll
    for (int mi = 0; mi < 4; ++mi)
#pragma unroll
      for (int ni = 0; ni < 4; ++ni)
        acc[mi][ni] = __builtin_amdgcn_mfma_i32_16x16x64_i8(a[mi], b[ni], acc[mi][ni], 0, 0, 0);

    __syncthreads();
  }

  // epilogue: C/D layout col=lane&15, row=quad*4+reg (dtype-independent, m121-128)
  float sc[4][4];
#pragma unroll
  for (int mi = 0; mi < 4; ++mi) {
    int rbase = m0 + wm * 64 + mi * 16 + quad * 4;
#pragma unroll
    for (int r = 0; r < 4; ++r) sc[mi][r] = rscale[rbase + r];
  }
#pragma unroll
  for (int ni = 0; ni < 4; ++ni) {
    int col = n0 + wn * 64 + ni * 16 + l16;
    float bv = bias[col];
#pragma unroll
    for (int mi = 0; mi < 4; ++mi) {
      int rbase = m0 + wm * 64 + mi * 16 + quad * 4;
#pragma unroll
      for (int r = 0; r < 4; ++r)
        out[(size_t)(rbase + r) * N + col] = (float)acc[mi][ni][r] * sc[mi][r] + bv;
    }
  }
}

extern "C" void kernel_launch(void* const* d_in, const int* in_sizes, int n_in,
                              void* d_out, int out_size, void* d_ws, size_t ws_size,
                              hipStream_t stream) {
  const float* x = (const float*)d_in[0];
  const float* kern = (const float*)d_in[1];
  const float* bias = (const float*)d_in[2];
  float* out = (float*)d_out;

  signed char* Xq = (signed char*)d_ws;                        // 32 MiB
  signed char* Wq = Xq + (size_t)M * K;                        // 16 MiB
  float* rscale = (float*)(Wq + (size_t)N * K);                // 32 KiB

  quant_x_kernel<<<M, 256, 0, stream>>>(x, Xq, rscale);
  sign_t_kernel<<<dim3(N / 64, K / 64), dim3(256), 0, stream>>>(kern, Wq);
  gemm_bin_kernel<<<dim3(N / BN, M / BM), 256, 0, stream>>>(Xq, Wq, rscale, bias, out);
}